// Round 8
// baseline (260.382 us; speedup 1.0000x reference)
//
#include <hip/hip_runtime.h>
#include <math.h>

// ---------------------------------------------------------------------------
// CrossAttention: B=8, N=M=2048, C=512, H=4, D=128, shared QKV weights (K==V)
// Pipeline (6 dispatches):
//   conv2    : F1,F2 fp32 -> bf16 ws (one dispatch)
//   wconv2   : W_qkv,W_proj fp32 [k][n] -> bf16 [n][k] ws (one dispatch)
//   gemm_bt  : [Q;KV] = [F1b;F2b] @ W + b  (fused, per-half scale, bf16 ws)
//   kv_transpose : KVT[bh][d][key] = KV^T  (16MB, aliases dead F2b)
//   cross_attn: X = softmax2(Q KV^T) KV    (64q/wave, 4-buf, 1 barrier/kt)
//   gemm_bt  : out = Xb @ Wp + bp          (fp32)
// ---------------------------------------------------------------------------

typedef __attribute__((ext_vector_type(8))) short s16x8;   // 8 bf16 = 4 VGPR
typedef __attribute__((ext_vector_type(4))) float f32x4;   // MFMA acc

#define C_DIM 512
#define HDIM  128
#define NROWS 16384           // B*N = B*M
#define SCALE_Q 0.04419417382415922f
#define LOG2E   1.4426950408889634f

__device__ __forceinline__ unsigned short f2bf(float f) {
    union { float f; unsigned u; } v; v.f = f;
    unsigned r = v.u + 0x7fffu + ((v.u >> 16) & 1u);   // RNE
    return (unsigned short)(r >> 16);
}

// async global->LDS, 16B per lane; lds dest = uniform base + lane*16
__device__ __forceinline__ void async16(const void* g, void* l) {
    __builtin_amdgcn_global_load_lds(
        (const __attribute__((address_space(1))) void*)g,
        (__attribute__((address_space(3))) void*)l, 16, 0, 0);
}

// ---------------------------------------------------------------------------
// fp32 -> bf16, 8 elements/thread; y-dim selects (src,dst) pair
// ---------------------------------------------------------------------------
__global__ __launch_bounds__(256)
void conv_bf16_2(const float* __restrict__ s0, const float* __restrict__ s1,
                 unsigned short* __restrict__ d0, unsigned short* __restrict__ d1,
                 int n8) {
    const float* src = blockIdx.y ? s1 : s0;
    unsigned short* dst = blockIdx.y ? d1 : d0;
    int i = blockIdx.x * 256 + threadIdx.x;
    if (i >= n8) return;
    float4 a = ((const float4*)src)[2 * i];
    float4 b = ((const float4*)src)[2 * i + 1];
    union { unsigned short us[8]; uint4 v; } o;
    o.us[0] = f2bf(a.x); o.us[1] = f2bf(a.y); o.us[2] = f2bf(a.z); o.us[3] = f2bf(a.w);
    o.us[4] = f2bf(b.x); o.us[5] = f2bf(b.y); o.us[6] = f2bf(b.z); o.us[7] = f2bf(b.w);
    ((uint4*)dst)[i] = o.v;
}

// ---------------------------------------------------------------------------
// W [k][n] fp32 -> Wt [n][k] bf16 (512x512), 64x64 tiles; z selects pair
// ---------------------------------------------------------------------------
__global__ __launch_bounds__(256)
void wconv_t2(const float* __restrict__ W0, const float* __restrict__ W1,
              unsigned short* __restrict__ T0, unsigned short* __restrict__ T1) {
    const float* W = blockIdx.z ? W1 : W0;
    unsigned short* Wt = blockIdx.z ? T1 : T0;
    __shared__ float t[64][65];
    const int k0 = blockIdx.y * 64, n0 = blockIdx.x * 64;
    const int c = threadIdx.x & 63, r0 = threadIdx.x >> 6;
#pragma unroll
    for (int r = r0; r < 64; r += 4)
        t[r][c] = W[(size_t)(k0 + r) * C_DIM + n0 + c];
    __syncthreads();
#pragma unroll
    for (int r = r0; r < 64; r += 4)
        Wt[(size_t)(n0 + r) * C_DIM + k0 + c] = f2bf(t[c][r]);
}

// ---------------------------------------------------------------------------
// KVT[(b*4+h)*128 + d][key] = KV[b*2048+key][h*128+d]   (bf16 -> bf16)
// 64x64 tiles; [64][66] LDS pad -> 2-way (free) banks both directions.
// ---------------------------------------------------------------------------
__global__ __launch_bounds__(256)
void kv_transpose(const unsigned short* __restrict__ KV,
                  unsigned short* __restrict__ KVT) {
    __shared__ unsigned short t[64][66];
    const int key0 = blockIdx.x * 64;
    const int d0   = blockIdx.y * 64;
    const int bh   = blockIdx.z;            // b*4 + h
    const int b    = bh >> 2, h = bh & 3;
    const int c = threadIdx.x & 63, r0 = threadIdx.x >> 6;
    const unsigned short* src = KV + ((size_t)(b * 2048 + key0)) * C_DIM + h * HDIM + d0;
#pragma unroll
    for (int r = r0; r < 64; r += 4)
        t[r][c] = src[(size_t)r * C_DIM + c];
    __syncthreads();
    unsigned short* dst = KVT + ((size_t)(bh * HDIM + d0)) * 2048 + key0;
#pragma unroll
    for (int r = r0; r < 64; r += 4)
        dst[(size_t)r * 2048 + c] = t[c][r];
}

// ---------------------------------------------------------------------------
// GEMM: C[rows x 512] = A[rows x 512] @ Wt^T + bias, all-bf16 inputs.
// 128x128 tile, BK=64 (8 k-iters), async global_load_lds staging.
// (unchanged)
// ---------------------------------------------------------------------------
template <int OUT_BF16>
__global__ __launch_bounds__(256, 3)
void gemm_bt(const unsigned short* __restrict__ A,
             const unsigned short* __restrict__ Bt,
             const float* __restrict__ bias,
             void* __restrict__ Cv, float oscTop, int topRows) {
    __shared__ __align__(16) unsigned short As[128][64];
    __shared__ __align__(16) unsigned short Bs[128][64];

    const int tid  = threadIdx.x;
    const int wid  = tid >> 6;
    const int lane = tid & 63;
    const int lr   = lane & 15;
    const int quad = lane >> 4;
    const int wm   = wid >> 1;
    const int wn   = wid & 1;
    const int rowBase = blockIdx.y * 128;
    const int colBase = blockIdx.x * 128;
    const int srow = lane >> 3;
    const int soff = srow * C_DIM + (((lane & 7) ^ (srow & 7)) * 8);
    const float osc = (rowBase < topRows) ? oscTop : 1.0f;

    f32x4 acc[4][4];
#pragma unroll
    for (int i = 0; i < 4; i++)
#pragma unroll
        for (int j = 0; j < 4; j++) acc[i][j] = (f32x4)0.0f;

    for (int kt = 0; kt < 8; kt++) {
        const int k0 = kt * 64;
        __syncthreads();
#pragma unroll
        for (int i = 0; i < 4; i++) {
            const int R = wid * 32 + i * 8;            // wave-uniform row block
            async16(A  + (size_t)(rowBase + R) * C_DIM + k0 + soff, &As[R][0]);
            async16(Bt + (size_t)(colBase + R) * C_DIM + k0 + soff, &Bs[R][0]);
        }
        __syncthreads();   // drains vmcnt before frag reads

#pragma unroll
        for (int s = 0; s < 2; s++) {
            s16x8 af[4], bf[4];
#pragma unroll
            for (int i = 0; i < 4; i++)
                af[i] = *(const s16x8*)&As[wm * 64 + i * 16 + lr][((s * 4 + quad) ^ (lr & 7)) * 8];
#pragma unroll
            for (int j = 0; j < 4; j++)
                bf[j] = *(const s16x8*)&Bs[wn * 64 + j * 16 + lr][((s * 4 + quad) ^ (lr & 7)) * 8];
#pragma unroll
            for (int i = 0; i < 4; i++)
#pragma unroll
                for (int j = 0; j < 4; j++)
                    acc[i][j] = __builtin_amdgcn_mfma_f32_16x16x32_bf16(af[i], bf[j], acc[i][j], 0, 0, 0);
        }
    }

    float bcol[4];
#pragma unroll
    for (int j = 0; j < 4; j++)
        bcol[j] = bias[colBase + wn * 64 + j * 16 + lr];
#pragma unroll
    for (int i = 0; i < 4; i++) {
#pragma unroll
        for (int j = 0; j < 4; j++) {
            const int col = colBase + wn * 64 + j * 16 + lr;
#pragma unroll
            for (int r = 0; r < 4; r++) {
                const int row = rowBase + wm * 64 + i * 16 + quad * 4 + r;
                float v = (acc[i][j][r] + bcol[j]) * osc;
                if (OUT_BF16)
                    ((unsigned short*)Cv)[(size_t)row * C_DIM + col] = f2bf(v);
                else
                    ((float*)Cv)[(size_t)row * C_DIM + col] = v;
            }
        }
    }
}

// ---------------------------------------------------------------------------
// Flash cross-attention v11. Grid 256 blocks (1-D, XCD-decoded), 256 thr,
// 4 waves, 64 q/wave (256-q block), 1 block/CU, 4 waves/CU (1/SIMD).
// v11 rationale (round-7 accounting): per-CU DS traffic scales with
// waves/CU (every wave re-reads the tile), so 64q/wave halves the DS floor
// (each kf/vf b128 feeds 4 MFMAs) and makes the kernel MFMA-bound
// (floor ~33us). At 1 wave/SIMD all hiding is ILP, so sync is relaxed:
//  - 4 LDS buffers, ONE barrier per kt. Order: issue stage kt+2 ->
//    vmcnt(16) (my tile-kt loads done) -> s_barrier (everyone's done) ->
//    compute. No end barrier: a lagging wave can still be reading tile
//    kt-1 while a leader stages kt+2; mod-4 spacing keeps those buffers
//    distinct (mod-3 would collide: kt+2 == kt-1 mod 3).
//  - K-half split: QK(keys 0..31) -> softmax -> PV, then keys 32..63;
//    phase-B kf reads are independent of phase-A PV -> ILP overlap.
// Swapped QK^T (P in-register, v10): s = mfma(K,Q), Kt row R holds key
// kappa(R) = 32*(R>>5) + 8*((R>>2)&3) + 4*((R>>4)&1) + (R&3) so each lane's
// QK output keys are exactly its PV A-fragment keys. XOR chunk swizzle
// (pos = chunk ^ (row&7)) pre-applied at the GLOBAL source (Kt from KV,
// Vt from KVT). Fixed-max softmax (Q pre-scaled); manual RNE f2bf.
// LDS = 4 * (16K Kt + 16K Vt) = 128KB. VGPR ~290 -> launch_bounds(256,1).
// ---------------------------------------------------------------------------
__global__ __launch_bounds__(256, 1)
void cross_attn(const unsigned short* __restrict__ Q,
                const unsigned short* __restrict__ KV,
                const unsigned short* __restrict__ KVT,
                unsigned short* __restrict__ X) {
    __shared__ __align__(16) unsigned short Kt[4][64][128];  // [buf][row][d] swizzled
    __shared__ __align__(16) unsigned short Vt[4][128][64];  // [buf][d][key] swizzled

    const int tid  = threadIdx.x;
    const int wid  = tid >> 6;        // 0..3
    const int lane = tid & 63;
    const int lr   = lane & 15;
    const int quad = lane >> 4;

    // XCD-aware decode: wg%8 = XCD. 256 blocks: 32 slots/XCD =
    // 4 (b,h) pairs x 8 xblk (256 q each).
    const int wg   = blockIdx.x;
    const int xcd  = wg & 7;
    const int slot = wg >> 3;         // 0..31
    const int p    = xcd + 8 * (slot & 3);
    const int xblk = slot >> 2;       // 0..7
    const int b    = p >> 2;
    const int h    = p & 3;
    const int hoff = h * HDIM;
    const size_t qrow0  = (size_t)b * 2048 + xblk * 256 + wid * 64;
    const size_t kvrow0 = (size_t)b * 2048;

    // Q fragments (pre-scaled by SCALE*log2e), B-operand of swapped QK:
    // lane holds q = i*16+lr, d = kk*32 + quad*8 + jj.   (64 VGPR)
    s16x8 qf[4][4];
#pragma unroll
    for (int i = 0; i < 4; i++)
#pragma unroll
        for (int kk = 0; kk < 4; kk++)
            qf[i][kk] = *(const s16x8*)(Q + (qrow0 + i * 16 + lr) * C_DIM + hoff + kk * 32 + quad * 8);

    // per-lane staging source pointers (key0 added at stage time).
    // Kt call a: LDS row R = wid*16 + a*4 + (lane>>4); key = kappa(R);
    //   chunk pos p' = lane&15 holds global chunk c = (p'&8) | ((p' ^ (R&7)) & 7).
    // Vt call a: LDS row d = wid*32 + a*8 + (lane>>3); pos p' = lane&7 holds
    //   key-chunk c = p' ^ (d&7) = (lane&7) ^ (lane>>3).
    const unsigned short* pK[4];
    const unsigned short* pV[4];
#pragma unroll
    for (int a = 0; a < 4; a++) {
        const int R   = wid * 16 + a * 4 + (lane >> 4);
        const int key = 32 * (R >> 5) + 8 * ((R >> 2) & 3) + 4 * ((R >> 4) & 1) + (R & 3);
        const int pp  = lane & 15;
        const int ck  = (pp & 8) | ((pp ^ (R & 7)) & 7);
        pK[a] = KV + (kvrow0 + key) * C_DIM + hoff + ck * 8;
        const int d  = wid * 32 + a * 8 + (lane >> 3);
        const int cv = (lane & 7) ^ (lane >> 3);
        pV[a] = KVT + ((size_t)((b * 4 + h) * HDIM + d)) * 2048 + cv * 8;
    }

    f32x4 O[4][8];                    // 128 VGPR
#pragma unroll
    for (int i = 0; i < 4; i++)
#pragma unroll
        for (int dt = 0; dt < 8; dt++) O[i][dt] = (f32x4)0.0f;
    float lacc[4];
#pragma unroll
    for (int i = 0; i < 4; i++) lacc[i] = 0.0f;

    // ---- prologue: stage tiles 0,1 into bufs 0,1 (8 async16/wave each) ----
#pragma unroll
    for (int t = 0; t < 2; t++) {
        const size_t key0 = (size_t)t * 64;
#pragma unroll
        for (int a = 0; a < 4; a++) {
            async16(pK[a] + key0 * C_DIM, &Kt[t][wid * 16 + a * 4][0]);
            async16(pV[a] + key0,         &Vt[t][wid * 32 + a * 8][0]);
        }
    }

    for (int kt = 0; kt < 32; kt++) {
        const int cur = kt & 3;
        // issue tile kt+2 into buf (kt+2)&3, then wait for MY tile-kt loads
        // (vmcnt(16): tiles kt+1, kt+2 in flight), then barrier.
        if (kt < 30) {
            const int nbuf = (kt + 2) & 3;
            const size_t key0 = (size_t)(kt + 2) * 64;
#pragma unroll
            for (int a = 0; a < 4; a++) {
                async16(pK[a] + key0 * C_DIM, &Kt[nbuf][wid * 16 + a * 4][0]);
                async16(pV[a] + key0,         &Vt[nbuf][wid * 32 + a * 8][0]);
            }
            asm volatile("s_waitcnt vmcnt(16)" ::: "memory");
        } else if (kt == 30) {
            asm volatile("s_waitcnt vmcnt(8)" ::: "memory");
        } else {
            asm volatile("s_waitcnt vmcnt(0)" ::: "memory");
        }
        __builtin_amdgcn_sched_barrier(0);
        __builtin_amdgcn_s_barrier();        // all waves: tile kt LDS complete
        __builtin_amdgcn_sched_barrier(0);

        // two key-halves: QK(32 keys) -> softmax -> PV, ILP-overlapped
#pragma unroll
        for (int half = 0; half < 2; half++) {
            // S^T = K Q^T : 8 kf reads, 32 MFMAs.
            // s[i][jh][r] = logit for key = half*32 + 8*quad + 4*jh + r,
            // q = i*16+lr.
            f32x4 s[4][2];
#pragma unroll
            for (int i = 0; i < 4; i++) {
                s[i][0] = (f32x4)0.0f; s[i][1] = (f32x4)0.0f;
            }
#pragma unroll
            for (int kk = 0; kk < 4; kk++) {
#pragma unroll
                for (int jh = 0; jh < 2; jh++) {
                    s16x8 kf = *(const s16x8*)&Kt[cur][(half * 2 + jh) * 16 + lr][((kk * 4 + quad) ^ (lr & 7)) * 8];
#pragma unroll
                    for (int i = 0; i < 4; i++)
                        s[i][jh] = __builtin_amdgcn_mfma_f32_16x16x32_bf16(kf, qf[i][kk], s[i][jh], 0, 0, 0);
                }
            }

            // fixed-max softmax in-register: pa[i] element jj <-> key
            // half*32 + quad*8 + jj (jj=4*jh+r).
            s16x8 pa[4];
#pragma unroll
            for (int i = 0; i < 4; i++) {
                float p0 = __builtin_amdgcn_exp2f(s[i][0][0]);
                float p1 = __builtin_amdgcn_exp2f(s[i][0][1]);
                float p2 = __builtin_amdgcn_exp2f(s[i][0][2]);
                float p3 = __builtin_amdgcn_exp2f(s[i][0][3]);
                float p4 = __builtin_amdgcn_exp2f(s[i][1][0]);
                float p5 = __builtin_amdgcn_exp2f(s[i][1][1]);
                float p6 = __builtin_amdgcn_exp2f(s[i][1][2]);
                float p7 = __builtin_amdgcn_exp2f(s[i][1][3]);
                lacc[i] += ((p0 + p1) + (p2 + p3)) + ((p4 + p5) + (p6 + p7));
                union { unsigned short us[8]; s16x8 v; } pu;
                pu.us[0] = f2bf(p0); pu.us[1] = f2bf(p1);
                pu.us[2] = f2bf(p2); pu.us[3] = f2bf(p3);
                pu.us[4] = f2bf(p4); pu.us[5] = f2bf(p5);
                pu.us[6] = f2bf(p6); pu.us[7] = f2bf(p7);
                pa[i] = pu.v;
            }

            // O += P V : 8 vf reads, 32 MFMAs (vf feeds all 4 i-blocks)
#pragma unroll
            for (int dt = 0; dt < 8; dt++) {
                s16x8 vf = *(const s16x8*)&Vt[cur][dt * 16 + lr][((half * 4 + quad) ^ (lr & 7)) * 8];
#pragma unroll
                for (int i = 0; i < 4; i++)
                    O[i][dt] = __builtin_amdgcn_mfma_f32_16x16x32_bf16(pa[i], vf, O[i][dt], 0, 0, 0);
            }
        }
        // no end barrier: 4-buffer spacing tolerates one-iter wave drift
    }

    // final l reduction: quad-axis (lanes sharing lr hold disjoint key sets)
    // then redistribute l[q=quad*4+r] via shfl; write X.
#pragma unroll
    for (int i = 0; i < 4; i++) {
        float l = lacc[i];
        l += __shfl_xor(l, 16);
        l += __shfl_xor(l, 32);          // all lanes: l_full[q = i*16+lr]
#pragma unroll
        for (int r = 0; r < 4; r++) {
            const float inv = 1.0f / __shfl(l, quad * 4 + r);  // q = i*16+quad*4+r
            const size_t row = (qrow0 + i * 16 + quad * 4 + r) * C_DIM + hoff;
#pragma unroll
            for (int dt = 0; dt < 8; dt++)
                X[row + dt * 16 + lr] = f2bf(O[i][dt][r] * inv);
        }
    }
}

// ---------------------------------------------------------------------------
extern "C" void kernel_launch(void* const* d_in, const int* in_sizes, int n_in,
                              void* d_out, int out_size, void* d_ws, size_t ws_size,
                              hipStream_t stream) {
    const float* F1     = (const float*)d_in[0];
    const float* F2     = (const float*)d_in[1];
    const float* W_qkv  = (const float*)d_in[2];
    const float* b_qkv  = (const float*)d_in[3];
    const float* W_proj = (const float*)d_in[4];
    const float* b_proj = (const float*)d_in[5];
    float* out = (float*)d_out;

    const size_t NC = (size_t)NROWS * C_DIM;       // 8.4M elems
    unsigned short* F1b = (unsigned short*)d_ws;   // 16MB (F1b||F2b contiguous)
    unsigned short* F2b = F1b + NC;                // 16MB
    unsigned short* Qw  = F2b + NC;                // 16MB (Qw||KVw contiguous)
    unsigned short* KVw = Qw  + NC;                // 16MB
    unsigned short* Wqt = KVw + NC;                // 0.5MB
    unsigned short* Wpt = Wqt + C_DIM * C_DIM;     // 0.5MB
    unsigned short* Xw  = F1b;                     // alias: F1b dead after QKV gemm
    unsigned short* KVT = F2b;                     // alias: F2b dead after QKV gemm

    dim3 blk(256);

    conv_bf16_2<<<dim3(NC / 8 / 256, 2), blk, 0, stream>>>(F1, F2, F1b, F2b, (int)(NC / 8));
    wconv_t2<<<dim3(8, 8, 2), blk, 0, stream>>>(W_qkv, W_proj, Wqt, Wpt);

    // fused Q+KV projection: 32768 rows, top half scaled by SCALE*log2e
    gemm_bt<1><<<dim3(4, 256), blk, 0, stream>>>(F1b, Wqt, b_qkv, Qw, SCALE_Q * LOG2E, NROWS);
    kv_transpose<<<dim3(32, 2, 32), blk, 0, stream>>>(KVw, KVT);
    cross_attn<<<dim3(256), blk, 0, stream>>>(Qw, KVw, KVT, Xw);
    gemm_bt<0><<<dim3(4, 128), blk, 0, stream>>>(Xw, Wpt, b_proj, out, 1.0f, 0);
}

// Round 9
// 239.344 us; speedup vs baseline: 1.0879x; 1.0879x over previous
//
#include <hip/hip_runtime.h>
#include <math.h>

// ---------------------------------------------------------------------------
// CrossAttention: B=8, N=M=2048, C=512, H=4, D=128, shared QKV weights (K==V)
// Pipeline (6 dispatches):
//   conv2    : F1,F2 fp32 -> bf16 ws (one dispatch)
//   wconv2   : W_qkv,W_proj fp32 [k][n] -> bf16 [n][k] ws (one dispatch)
//   gemm_bt  : [Q;KV] = [F1b;F2b] @ W + b  (fused, per-half scale, bf16 ws)
//   kv_transpose : KVT[bh][d][key] = KV^T  (16MB, aliases dead F2b)
//   cross_attn: X = softmax2(Q KV^T) KV    (8-wave, 4-buf, 1 barrier/kt)
//   gemm_bt  : out = Xb @ Wp + bp          (fp32)
// ---------------------------------------------------------------------------

typedef __attribute__((ext_vector_type(8))) short s16x8;   // 8 bf16 = 4 VGPR
typedef __attribute__((ext_vector_type(4))) float f32x4;   // MFMA acc

#define C_DIM 512
#define HDIM  128
#define NROWS 16384           // B*N = B*M
#define SCALE_Q 0.04419417382415922f
#define LOG2E   1.4426950408889634f

__device__ __forceinline__ unsigned short f2bf(float f) {
    union { float f; unsigned u; } v; v.f = f;
    unsigned r = v.u + 0x7fffu + ((v.u >> 16) & 1u);   // RNE
    return (unsigned short)(r >> 16);
}

// async global->LDS, 16B per lane; lds dest = uniform base + lane*16
__device__ __forceinline__ void async16(const void* g, void* l) {
    __builtin_amdgcn_global_load_lds(
        (const __attribute__((address_space(1))) void*)g,
        (__attribute__((address_space(3))) void*)l, 16, 0, 0);
}

// ---------------------------------------------------------------------------
// fp32 -> bf16, 8 elements/thread; y-dim selects (src,dst) pair
// ---------------------------------------------------------------------------
__global__ __launch_bounds__(256)
void conv_bf16_2(const float* __restrict__ s0, const float* __restrict__ s1,
                 unsigned short* __restrict__ d0, unsigned short* __restrict__ d1,
                 int n8) {
    const float* src = blockIdx.y ? s1 : s0;
    unsigned short* dst = blockIdx.y ? d1 : d0;
    int i = blockIdx.x * 256 + threadIdx.x;
    if (i >= n8) return;
    float4 a = ((const float4*)src)[2 * i];
    float4 b = ((const float4*)src)[2 * i + 1];
    union { unsigned short us[8]; uint4 v; } o;
    o.us[0] = f2bf(a.x); o.us[1] = f2bf(a.y); o.us[2] = f2bf(a.z); o.us[3] = f2bf(a.w);
    o.us[4] = f2bf(b.x); o.us[5] = f2bf(b.y); o.us[6] = f2bf(b.z); o.us[7] = f2bf(b.w);
    ((uint4*)dst)[i] = o.v;
}

// ---------------------------------------------------------------------------
// W [k][n] fp32 -> Wt [n][k] bf16 (512x512), 64x64 tiles; z selects pair
// ---------------------------------------------------------------------------
__global__ __launch_bounds__(256)
void wconv_t2(const float* __restrict__ W0, const float* __restrict__ W1,
              unsigned short* __restrict__ T0, unsigned short* __restrict__ T1) {
    const float* W = blockIdx.z ? W1 : W0;
    unsigned short* Wt = blockIdx.z ? T1 : T0;
    __shared__ float t[64][65];
    const int k0 = blockIdx.y * 64, n0 = blockIdx.x * 64;
    const int c = threadIdx.x & 63, r0 = threadIdx.x >> 6;
#pragma unroll
    for (int r = r0; r < 64; r += 4)
        t[r][c] = W[(size_t)(k0 + r) * C_DIM + n0 + c];
    __syncthreads();
#pragma unroll
    for (int r = r0; r < 64; r += 4)
        Wt[(size_t)(n0 + r) * C_DIM + k0 + c] = f2bf(t[c][r]);
}

// ---------------------------------------------------------------------------
// KVT[(b*4+h)*128 + d][key] = KV[b*2048+key][h*128+d]   (bf16 -> bf16)
// 64x64 tiles; [64][66] LDS pad -> 2-way (free) banks both directions.
// ---------------------------------------------------------------------------
__global__ __launch_bounds__(256)
void kv_transpose(const unsigned short* __restrict__ KV,
                  unsigned short* __restrict__ KVT) {
    __shared__ unsigned short t[64][66];
    const int key0 = blockIdx.x * 64;
    const int d0   = blockIdx.y * 64;
    const int bh   = blockIdx.z;            // b*4 + h
    const int b    = bh >> 2, h = bh & 3;
    const int c = threadIdx.x & 63, r0 = threadIdx.x >> 6;
    const unsigned short* src = KV + ((size_t)(b * 2048 + key0)) * C_DIM + h * HDIM + d0;
#pragma unroll
    for (int r = r0; r < 64; r += 4)
        t[r][c] = src[(size_t)r * C_DIM + c];
    __syncthreads();
    unsigned short* dst = KVT + ((size_t)(bh * HDIM + d0)) * 2048 + key0;
#pragma unroll
    for (int r = r0; r < 64; r += 4)
        dst[(size_t)r * 2048 + c] = t[c][r];
}

// ---------------------------------------------------------------------------
// GEMM: C[rows x 512] = A[rows x 512] @ Wt^T + bias, all-bf16 inputs.
// 128x128 tile, BK=64 (8 k-iters), async global_load_lds staging.
// (unchanged)
// ---------------------------------------------------------------------------
template <int OUT_BF16>
__global__ __launch_bounds__(256, 3)
void gemm_bt(const unsigned short* __restrict__ A,
             const unsigned short* __restrict__ Bt,
             const float* __restrict__ bias,
             void* __restrict__ Cv, float oscTop, int topRows) {
    __shared__ __align__(16) unsigned short As[128][64];
    __shared__ __align__(16) unsigned short Bs[128][64];

    const int tid  = threadIdx.x;
    const int wid  = tid >> 6;
    const int lane = tid & 63;
    const int lr   = lane & 15;
    const int quad = lane >> 4;
    const int wm   = wid >> 1;
    const int wn   = wid & 1;
    const int rowBase = blockIdx.y * 128;
    const int colBase = blockIdx.x * 128;
    const int srow = lane >> 3;
    const int soff = srow * C_DIM + (((lane & 7) ^ (srow & 7)) * 8);
    const float osc = (rowBase < topRows) ? oscTop : 1.0f;

    f32x4 acc[4][4];
#pragma unroll
    for (int i = 0; i < 4; i++)
#pragma unroll
        for (int j = 0; j < 4; j++) acc[i][j] = (f32x4)0.0f;

    for (int kt = 0; kt < 8; kt++) {
        const int k0 = kt * 64;
        __syncthreads();
#pragma unroll
        for (int i = 0; i < 4; i++) {
            const int R = wid * 32 + i * 8;            // wave-uniform row block
            async16(A  + (size_t)(rowBase + R) * C_DIM + k0 + soff, &As[R][0]);
            async16(Bt + (size_t)(colBase + R) * C_DIM + k0 + soff, &Bs[R][0]);
        }
        __syncthreads();   // drains vmcnt before frag reads

#pragma unroll
        for (int s = 0; s < 2; s++) {
            s16x8 af[4], bf[4];
#pragma unroll
            for (int i = 0; i < 4; i++)
                af[i] = *(const s16x8*)&As[wm * 64 + i * 16 + lr][((s * 4 + quad) ^ (lr & 7)) * 8];
#pragma unroll
            for (int j = 0; j < 4; j++)
                bf[j] = *(const s16x8*)&Bs[wn * 64 + j * 16 + lr][((s * 4 + quad) ^ (lr & 7)) * 8];
#pragma unroll
            for (int i = 0; i < 4; i++)
#pragma unroll
                for (int j = 0; j < 4; j++)
                    acc[i][j] = __builtin_amdgcn_mfma_f32_16x16x32_bf16(af[i], bf[j], acc[i][j], 0, 0, 0);
        }
    }

    float bcol[4];
#pragma unroll
    for (int j = 0; j < 4; j++)
        bcol[j] = bias[colBase + wn * 64 + j * 16 + lr];
#pragma unroll
    for (int i = 0; i < 4; i++) {
#pragma unroll
        for (int j = 0; j < 4; j++) {
            const int col = colBase + wn * 64 + j * 16 + lr;
#pragma unroll
            for (int r = 0; r < 4; r++) {
                const int row = rowBase + wm * 64 + i * 16 + quad * 4 + r;
                float v = (acc[i][j][r] + bcol[j]) * osc;
                if (OUT_BF16)
                    ((unsigned short*)Cv)[(size_t)row * C_DIM + col] = f2bf(v);
                else
                    ((float*)Cv)[(size_t)row * C_DIM + col] = v;
            }
        }
    }
}

// ---------------------------------------------------------------------------
// Flash cross-attention v12. Grid 256 blocks (1-D, XCD-decoded), 512 thr,
// 8 waves, 32 q/wave (256-q block), 1 block/CU, 8 waves/CU (2/SIMD).
// v12 = v10's compute operating point (32q/wave, 2 waves/SIMD -- best so
// far, 81.6us) + v11's validated relaxed schedule (4 LDS buffers, ONE
// barrier per kt, no end-of-kt lgkm drain). v11 proved the schedule
// correct; its regression was the 1-wave/SIMD occupancy, not the sync.
// Drift safety: a wave issues STAGE(kt+3) only after barrier(kt), which
// guarantees all waves finished COMPUTE(kt-1) = last readers of buf
// (kt-1)&3 = (kt+3)&3. Compiler's per-use lgkm waits ensure a wave's LDS
// reads are consumed before it advances. kt-loop unrolled x4 so all LDS
// buffer offsets are immediates; s_setprio(1) wraps the MFMA clusters (T5).
// Swapped QK^T (P in-register): s = mfma(K,Q); Kt row R holds key
// kappa(R) = 32*(R>>5) + 8*((R>>2)&3) + 4*((R>>4)&1) + (R&3) so each lane's
// QK output keys are exactly its PV A-fragment keys. XOR chunk swizzle
// (pos = chunk ^ (row&7)) pre-applied at the GLOBAL source (Kt from KV,
// Vt from KVT). Fixed-max softmax (Q pre-scaled); manual RNE f2bf
// (v_cvt_pk_bf16_f32 truncates -- round-4 failure).
// LDS = 4 * (16K Kt + 16K Vt) = 128KB -> 1 block/CU.
// ---------------------------------------------------------------------------
__global__ __launch_bounds__(512, 2)
void cross_attn(const unsigned short* __restrict__ Q,
                const unsigned short* __restrict__ KV,
                const unsigned short* __restrict__ KVT,
                unsigned short* __restrict__ X) {
    __shared__ __align__(16) unsigned short Kt[4][64][128];  // [buf][row][d] swizzled
    __shared__ __align__(16) unsigned short Vt[4][128][64];  // [buf][d][key] swizzled

    const int tid  = threadIdx.x;
    const int wid  = tid >> 6;        // 0..7
    const int lane = tid & 63;
    const int lr   = lane & 15;
    const int quad = lane >> 4;

    // XCD-aware decode: wg%8 = XCD. 256 blocks: 32 slots/XCD =
    // 4 (b,h) pairs x 8 xblk (256 q each).
    const int wg   = blockIdx.x;
    const int xcd  = wg & 7;
    const int slot = wg >> 3;         // 0..31
    const int p    = xcd + 8 * (slot & 3);
    const int xblk = slot >> 2;       // 0..7
    const int b    = p >> 2;
    const int h    = p & 3;
    const int hoff = h * HDIM;
    const size_t qrow0  = (size_t)b * 2048 + xblk * 256 + wid * 32;
    const size_t kvrow0 = (size_t)b * 2048;

    // Q fragments (pre-scaled by SCALE*log2e), B-operand of swapped QK:
    // lane holds q = i*16+lr, d = kk*32 + quad*8 + jj.
    s16x8 qf[2][4];
#pragma unroll
    for (int i = 0; i < 2; i++)
#pragma unroll
        for (int kk = 0; kk < 4; kk++)
            qf[i][kk] = *(const s16x8*)(Q + (qrow0 + i * 16 + lr) * C_DIM + hoff + kk * 32 + quad * 8);

    // per-lane staging source pointers (key0 added at stage time); 8 waves
    // split the tile: wave stages Kt rows wid*8+a*4.. and Vt rows wid*16+a*8..
    // Kt call a: LDS row R = wid*8 + a*4 + (lane>>4); key = kappa(R);
    //   chunk pos p' = lane&15 holds global chunk c = (p'&8) | ((p' ^ (R&7)) & 7).
    // Vt call a: LDS row d = wid*16 + a*8 + (lane>>3); pos p' = lane&7 holds
    //   key-chunk c = p' ^ (d&7) = (lane&7) ^ (lane>>3).
    const unsigned short* pK[2];
    const unsigned short* pV[2];
#pragma unroll
    for (int a = 0; a < 2; a++) {
        const int R   = wid * 8 + a * 4 + (lane >> 4);
        const int key = 32 * (R >> 5) + 8 * ((R >> 2) & 3) + 4 * ((R >> 4) & 1) + (R & 3);
        const int pp  = lane & 15;
        const int ck  = (pp & 8) | ((pp ^ (R & 7)) & 7);
        pK[a] = KV + (kvrow0 + key) * C_DIM + hoff + ck * 8;
        const int d  = wid * 16 + a * 8 + (lane >> 3);
        const int cv = (lane & 7) ^ (lane >> 3);
        pV[a] = KVT + ((size_t)((b * 4 + h) * HDIM + d)) * 2048 + cv * 8;
    }

    f32x4 O[2][8];
#pragma unroll
    for (int i = 0; i < 2; i++)
#pragma unroll
        for (int dt = 0; dt < 8; dt++) O[i][dt] = (f32x4)0.0f;
    float lacc[2];
    lacc[0] = 0.0f; lacc[1] = 0.0f;

    // stage tile t into buffer buf (2 K + 2 V async16 per wave)
    auto STAGE = [&](int t, int buf) {
        const size_t key0 = (size_t)t * 64;
#pragma unroll
        for (int a = 0; a < 2; a++) {
            async16(pK[a] + key0 * C_DIM, &Kt[buf][wid * 8 + a * 4][0]);
            async16(pV[a] + key0,         &Vt[buf][wid * 16 + a * 8][0]);
        }
    };

    // full compute of the tile in buffer cur (v10 body)
    auto COMPUTE = [&](int cur) {
        // S^T = K Q^T : 32 MFMAs. s[i][j][r] = logit for
        // key = 32*(j>>1) + 8*quad + 4*(j&1) + r, q = i*16+lr.
        f32x4 s[2][4];
#pragma unroll
        for (int i = 0; i < 2; i++)
#pragma unroll
            for (int j = 0; j < 4; j++) s[i][j] = (f32x4)0.0f;
        __builtin_amdgcn_s_setprio(1);
#pragma unroll
        for (int kk = 0; kk < 4; kk++) {
#pragma unroll
            for (int j = 0; j < 4; j++) {
                s16x8 kf = *(const s16x8*)&Kt[cur][j * 16 + lr][((kk * 4 + quad) ^ (lr & 7)) * 8];
                s[0][j] = __builtin_amdgcn_mfma_f32_16x16x32_bf16(kf, qf[0][kk], s[0][j], 0, 0, 0);
                s[1][j] = __builtin_amdgcn_mfma_f32_16x16x32_bf16(kf, qf[1][kk], s[1][j], 0, 0, 0);
            }
        }
        __builtin_amdgcn_s_setprio(0);

        // fixed-max softmax fully in-register: exp2 + RNE pack into the PV
        // A-fragment. pa[i][kk] element jj <-> key kk*32 + quad*8 + jj.
        s16x8 pa[2][2];
#pragma unroll
        for (int i = 0; i < 2; i++) {
#pragma unroll
            for (int kk = 0; kk < 2; kk++) {
                float p0 = __builtin_amdgcn_exp2f(s[i][2 * kk][0]);
                float p1 = __builtin_amdgcn_exp2f(s[i][2 * kk][1]);
                float p2 = __builtin_amdgcn_exp2f(s[i][2 * kk][2]);
                float p3 = __builtin_amdgcn_exp2f(s[i][2 * kk][3]);
                float p4 = __builtin_amdgcn_exp2f(s[i][2 * kk + 1][0]);
                float p5 = __builtin_amdgcn_exp2f(s[i][2 * kk + 1][1]);
                float p6 = __builtin_amdgcn_exp2f(s[i][2 * kk + 1][2]);
                float p7 = __builtin_amdgcn_exp2f(s[i][2 * kk + 1][3]);
                lacc[i] += ((p0 + p1) + (p2 + p3)) + ((p4 + p5) + (p6 + p7));
                union { unsigned short us[8]; s16x8 v; } pu;
                pu.us[0] = f2bf(p0); pu.us[1] = f2bf(p1);
                pu.us[2] = f2bf(p2); pu.us[3] = f2bf(p3);
                pu.us[4] = f2bf(p4); pu.us[5] = f2bf(p5);
                pu.us[6] = f2bf(p6); pu.us[7] = f2bf(p7);
                pa[i][kk] = pu.v;
            }
        }

        // O += P V  (vf softmax-independent; feeds both i-blocks)
        __builtin_amdgcn_s_setprio(1);
#pragma unroll
        for (int kk = 0; kk < 2; kk++) {
#pragma unroll
            for (int dt = 0; dt < 8; dt++) {
                s16x8 vf = *(const s16x8*)&Vt[cur][dt * 16 + lr][((kk * 4 + quad) ^ (lr & 7)) * 8];
                O[0][dt] = __builtin_amdgcn_mfma_f32_16x16x32_bf16(pa[0][kk], vf, O[0][dt], 0, 0, 0);
                O[1][dt] = __builtin_amdgcn_mfma_f32_16x16x32_bf16(pa[1][kk], vf, O[1][dt], 0, 0, 0);
            }
        }
        __builtin_amdgcn_s_setprio(0);
    };

    // ---- prologue: stage tiles 0,1 into bufs 0,1 ----
    STAGE(0, 0);
    STAGE(1, 1);

    // main loop: ONE barrier per kt; stage runs 2 tiles ahead.
    // vmcnt(8): per wave, 4 calls/tile; waiting to <=8 outstanding retires
    // everything older than tiles kt+1,kt+2 -> tile kt complete.
#pragma unroll 4
    for (int kt = 0; kt < 28; kt++) {
        STAGE(kt + 2, (kt + 2) & 3);
        asm volatile("s_waitcnt vmcnt(8)" ::: "memory");
        __builtin_amdgcn_sched_barrier(0);
        __builtin_amdgcn_s_barrier();
        __builtin_amdgcn_sched_barrier(0);
        COMPUTE(kt & 3);
    }
    // epilogue: kt = 28..31
    STAGE(30, 2);
    asm volatile("s_waitcnt vmcnt(8)" ::: "memory");
    __builtin_amdgcn_sched_barrier(0);
    __builtin_amdgcn_s_barrier();
    __builtin_amdgcn_sched_barrier(0);
    COMPUTE(0);

    STAGE(31, 3);
    asm volatile("s_waitcnt vmcnt(8)" ::: "memory");
    __builtin_amdgcn_sched_barrier(0);
    __builtin_amdgcn_s_barrier();
    __builtin_amdgcn_sched_barrier(0);
    COMPUTE(1);

    asm volatile("s_waitcnt vmcnt(4)" ::: "memory");
    __builtin_amdgcn_sched_barrier(0);
    __builtin_amdgcn_s_barrier();
    __builtin_amdgcn_sched_barrier(0);
    COMPUTE(2);

    asm volatile("s_waitcnt vmcnt(0)" ::: "memory");
    __builtin_amdgcn_sched_barrier(0);
    __builtin_amdgcn_s_barrier();
    __builtin_amdgcn_sched_barrier(0);
    COMPUTE(3);

    // final l reduction: quad-axis (lanes sharing lr hold disjoint key sets)
    // then redistribute l[q=quad*4+r] via shfl; write X.
#pragma unroll
    for (int i = 0; i < 2; i++) {
        float l = lacc[i];
        l += __shfl_xor(l, 16);
        l += __shfl_xor(l, 32);          // all lanes: l_full[q = i*16+lr]
#pragma unroll
        for (int r = 0; r < 4; r++) {
            const float inv = 1.0f / __shfl(l, quad * 4 + r);  // q = i*16+quad*4+r
            const size_t row = (qrow0 + i * 16 + quad * 4 + r) * C_DIM + hoff;
#pragma unroll
            for (int dt = 0; dt < 8; dt++)
                X[row + dt * 16 + lr] = f2bf(O[i][dt][r] * inv);
        }
    }
}

// ---------------------------------------------------------------------------
extern "C" void kernel_launch(void* const* d_in, const int* in_sizes, int n_in,
                              void* d_out, int out_size, void* d_ws, size_t ws_size,
                              hipStream_t stream) {
    const float* F1     = (const float*)d_in[0];
    const float* F2     = (const float*)d_in[1];
    const float* W_qkv  = (const float*)d_in[2];
    const float* b_qkv  = (const float*)d_in[3];
    const float* W_proj = (const float*)d_in[4];
    const float* b_proj = (const float*)d_in[5];
    float* out = (float*)d_out;

    const size_t NC = (size_t)NROWS * C_DIM;       // 8.4M elems
    unsigned short* F1b = (unsigned short*)d_ws;   // 16MB (F1b||F2b contiguous)
    unsigned short* F2b = F1b + NC;                // 16MB
    unsigned short* Qw  = F2b + NC;                // 16MB (Qw||KVw contiguous)
    unsigned short* KVw = Qw  + NC;                // 16MB
    unsigned short* Wqt = KVw + NC;                // 0.5MB
    unsigned short* Wpt = Wqt + C_DIM * C_DIM;     // 0.5MB
    unsigned short* Xw  = F1b;                     // alias: F1b dead after QKV gemm
    unsigned short* KVT = F2b;                     // alias: F2b dead after QKV gemm

    dim3 blk(256);

    conv_bf16_2<<<dim3(NC / 8 / 256, 2), blk, 0, stream>>>(F1, F2, F1b, F2b, (int)(NC / 8));
    wconv_t2<<<dim3(8, 8, 2), blk, 0, stream>>>(W_qkv, W_proj, Wqt, Wpt);

    // fused Q+KV projection: 32768 rows, top half scaled by SCALE*log2e
    gemm_bt<1><<<dim3(4, 256), blk, 0, stream>>>(F1b, Wqt, b_qkv, Qw, SCALE_Q * LOG2E, NROWS);
    kv_transpose<<<dim3(32, 2, 32), blk, 0, stream>>>(KVw, KVT);
    cross_attn<<<dim3(256), dim3(512), 0, stream>>>(Qw, KVw, KVT, Xw);
    gemm_bt<0><<<dim3(4, 128), blk, 0, stream>>>(Xw, Wpt, b_proj, out, 1.0f, 0);
}